// Round 10
// baseline (565.391 us; speedup 1.0000x reference)
//
#include <hip/hip_runtime.h>
#include <hip/hip_bf16.h>
#include <stdint.h>

#define AS1 __attribute__((address_space(1)))
#define AS3 __attribute__((address_space(3)))

typedef __attribute__((ext_vector_type(8))) short short8v;
typedef __attribute__((ext_vector_type(4))) float float4v;

#define NT 64
#define CCH 256
#define HH 56
#define WW 56
#define HWSZ 3136
#define HP 58
#define WP 58

// workspace layout (bytes)
#define OFF_XT   0ull
#define SZ_XT    110231552ull          // 64*58*58*256*2  (bf16 NHWC padded)
#define OFF_WPK  (OFF_XT + SZ_XT)
#define SZ_WPK   1179648ull            // 9*256*256*2
#define OFF_CS   (OFF_WPK + SZ_WPK)
#define SZ_CS    65536ull              // 64*256 f32 channel sums
#define OFF_XG2  (OFF_CS + SZ_CS)
#define SZ_XG2   8192ull               // 8*256 f32
#define OFF_WGT  (OFF_XG2 + SZ_XG2)
#define SZ_WGT   24576ull              // 8*256*3 f32
#define OFF_M    (OFF_WGT + SZ_WGT)
#define SZ_M     65536ull              // 8*256*8 f32
#define OFF_GATE (OFF_M + SZ_M)
#define SZ_GATE  65536ull              // 64*256 f32

__device__ __forceinline__ unsigned short f2bf(float f) {
    unsigned int u = __float_as_uint(f);
    unsigned int r = (u + 0x7fffu + ((u >> 16) & 1u)) >> 16;
    return (unsigned short)r;
}

__device__ __forceinline__ void gload16(const unsigned short* g, unsigned short* l) {
    __builtin_amdgcn_global_load_lds((const AS1 void*)g, (AS3 void*)l, 16, 0, 0);
}

// ---------------- K0: NCHW f32 -> NHWC-padded bf16 (with zero borders) ----
__global__ __launch_bounds__(256) void k0_transpose(const float* __restrict__ x,
                                                    unsigned short* __restrict__ xt) {
    int b = blockIdx.x;              // (nt, h, cb) : 64*56*4
    int cb = b & 3;
    int h  = (b >> 2) % 56;
    int nt = b / (4 * 56);
    int c0 = cb * 64;
    int tid = threadIdx.x;

    __shared__ float xs[64 * 57];    // padded stride 57 to dodge bank conflicts

    const float* src = x + ((size_t)nt * CCH + c0) * HWSZ + h * WW;
    for (int li = tid; li < 896; li += 256) {       // 64 rows * 14 float4
        int row = li / 14, f4 = li % 14;
        float4v v = *(const float4v*)(src + (size_t)row * HWSZ + f4 * 4);
        float* d = &xs[row * 57 + f4 * 4];
        d[0] = v.x; d[1] = v.y; d[2] = v.z; d[3] = v.w;
    }
    __syncthreads();

    unsigned short* dst = xt + (((size_t)nt * HP + (h + 1)) * WP) * CCH + c0;
    for (int job = tid; job < 464; job += 256) {    // 58 ww * 8 cgroups
        int ww = job >> 3, cg = job & 7;
        short8v v;
        if (ww == 0 || ww == 57) {
            v = (short8v){0,0,0,0,0,0,0,0};
        } else {
            #pragma unroll
            for (int jj = 0; jj < 8; ++jj)
                v[jj] = (short)f2bf(xs[(cg * 8 + jj) * 57 + (ww - 1)]);
        }
        *(short8v*)(dst + ww * CCH + cg * 8) = v;
    }
    if (h == 0) {   // zero rows hh=0 and hh=57
        unsigned short* d0  = xt + ((size_t)nt * HP + 0)  * WP * CCH + c0;
        unsigned short* d57 = xt + ((size_t)nt * HP + 57) * WP * CCH + c0;
        short8v z = (short8v){0,0,0,0,0,0,0,0};
        for (int job = tid; job < 464; job += 256) {
            int ww = job >> 3, cg = job & 7;
            *(short8v*)(d0  + ww * CCH + cg * 8) = z;
            *(short8v*)(d57 + ww * CCH + cg * 8) = z;
        }
    }
}

// ---------------- KW: pack conv weights -> [rs][k][c] bf16 ----------------
__global__ __launch_bounds__(256) void kw_pack(const float* __restrict__ nw,
                                               unsigned short* __restrict__ wpk) {
    int idx = blockIdx.x * 256 + threadIdx.x;       // 9*256*256 = 589824
    int rs = idx >> 16;
    int k  = (idx >> 8) & 255;
    int c  = idx & 255;
    wpk[idx] = f2bf(nw[(k * 256 + c) * 9 + rs]);
}

// ---------------- conv: implicit GEMM, 256x128x32 ----------------------
// R10: LDS holds A (weights) ONLY, 3-ring of 16KB slots (48 KB/block).
// B (pixels) goes global->registers directly (per-lane addresses match the
// MFMA B-frag layout; xt is L3-resident; each wave's 1KB load = 16 fully-
// used 64B lines).  A-frags register-double-buffered: tile t+1's 8 ds_reads
// issue DURING tile t's MFMA cluster -> LDS port (~1000 cyc/pair) hides
// under MFMA (~1030 cyc/pair) instead of serializing (R8/R9's 43-46% cap).
// Unroll-by-2 with named reg sets (rule 20).  Manual vmcnt only seals the
// cross-wave A staging (drain through A(t+1) at top of t); compiler's
// auto-waits cover B(vmcnt) and A-frag(lgkm) register deps.
// Issue order invariant at top of t: [A(t+1), B(t), A(t+2), B(t+1)]
//   -> drain thru A(t+1) = vmcnt(12); t=70: vmcnt(8); t=71: vmcnt(0).

#define STGA(sl_, tA_) do { \
    gload16(wpk + (tA_) + aoffg0, &lds[(sl_) * 8192 + ldsa0]); \
    gload16(wpk + (tA_) + aoffg1, &lds[(sl_) * 8192 + ldsa1]); \
    gload16(wpk + (tA_) + aoffg2, &lds[(sl_) * 8192 + ldsa2]); \
    gload16(wpk + (tA_) + aoffg3, &lds[(sl_) * 8192 + ldsa3]); \
} while (0)

#define LDAF(sl_, mi) (*(const short8v*)&lds[(sl_) * 8192 + (wm * 128 + (mi) * 16 + r16) * 32 + pA * 8])

#define VMWAIT_(n) asm volatile("s_waitcnt vmcnt(" #n ")" ::: "memory")
#define VMWAIT(n) VMWAIT_(n)

// One K-tile.  ACUR/BCUR: operands for tile kt (already in regs).
// ANXT/BNXT: filled for tile kt+1.  HAS2: stage A(kt+2); HAS1: load B(kt+1)
// + read A(kt+1) frags.  VMC: manual vmcnt immediate.
#define TILE(ACUR, ANXT, BCUR, BNXT, kt_, sl_, HAS2, HAS1, VMC) do { \
    if (HAS2) { \
        int sl2 = (sl_) + 2; if (sl2 >= 3) sl2 -= 3; \
        const int ktn2 = (kt_) + 2; \
        STGA(sl2, (ktn2 >> 3) * 65536 + (ktn2 & 7) * 32); \
    } \
    if (HAS1) { \
        const int ktn1 = (kt_) + 1; \
        const int rsn = ktn1 >> 3, con = (ktn1 & 7) * 32; \
        const int tBn = ((rsn / 3) * WP + (rsn - (rsn / 3) * 3)) * 256 + con; \
        BNXT[0] = *(const short8v*)(xt + bAddr0 + tBn); \
        BNXT[1] = *(const short8v*)(xt + bAddr1 + tBn); \
        BNXT[2] = *(const short8v*)(xt + bAddr2 + tBn); \
        BNXT[3] = *(const short8v*)(xt + bAddr3 + tBn); \
    } \
    VMWAIT(VMC); \
    __builtin_amdgcn_s_barrier(); \
    __builtin_amdgcn_sched_barrier(0); \
    if (HAS1) { \
        int sl1 = (sl_) + 1; if (sl1 >= 3) sl1 -= 3; \
        _Pragma("unroll") \
        for (int mi = 0; mi < 8; ++mi) ANXT[mi] = LDAF(sl1, mi); \
    } \
    __builtin_amdgcn_s_setprio(1); \
    _Pragma("unroll") \
    for (int j = 0; j < 4; ++j) \
        _Pragma("unroll") \
        for (int mi = 0; mi < 8; ++mi) \
            acc[mi][j] = __builtin_amdgcn_mfma_f32_16x16x32_bf16(ACUR[mi], BCUR[j], acc[mi][j], 0, 0, 0); \
    __builtin_amdgcn_s_setprio(0); \
    __builtin_amdgcn_s_barrier(); \
    __builtin_amdgcn_sched_barrier(0); \
} while (0)

__global__ __launch_bounds__(256, 2) void conv_mfma(const unsigned short* __restrict__ xt,
                                                    const unsigned short* __restrict__ wpk,
                                                    const float* __restrict__ net_b,
                                                    float* __restrict__ out,
                                                    float* __restrict__ chansum) {
    __shared__ unsigned short lds[24576];  // 48 KB: A ring 3 x 8192 shorts

    const int tid  = threadIdx.x;
    const int lane = tid & 63;
    const int wid  = tid >> 6;         // 0..3
    const int wm   = wid >> 1;         // 0..1  (m half, 128 rows)
    const int wp   = wid & 1;          // 0..1  (pixel half, 64 px)
    const int r16  = lane & 15;
    const int hi   = lane >> 4;        // 0..3  (k-chunk)
    const int pA   = (hi + (r16 >> 1)) & 3;   // rotation-swizzle read position

    // XCD-aware bijective swizzle: 1568 = 8 * 196
    const int pblk = (blockIdx.x & 7) * 196 + (blockIdx.x >> 3);
    const int p0 = pblk * 128;

    // A staging: 1024 chunks of 16B; thread's chunks = tid + 256*i.
    // slot s -> row r = s>>2, pos p = s&3, holds global chunk (p-(r>>1))&3.
    int aoffg0, aoffg1, aoffg2, aoffg3;
    const int ldsa0 = tid * 8,         ldsa1 = (tid + 256) * 8;
    const int ldsa2 = (tid + 512) * 8, ldsa3 = (tid + 768) * 8;
    {
        #pragma unroll
        for (int i = 0; i < 4; ++i) {
            int ch = tid + 256 * i;
            int r = ch >> 2;
            int cg = ((ch & 3) - (r >> 1)) & 3;
            int off = r * 256 + cg * 8;
            if (i == 0) aoffg0 = off; else if (i == 1) aoffg1 = off;
            else if (i == 2) aoffg2 = off; else aoffg3 = off;
        }
    }

    // B per-lane base offsets (shorts) into xt for the 4 j-frags:
    // pixel = p0 + wp*64 + j*16 + r16, k-chunk = hi (within the tile's 32-k).
    int bAddr0, bAddr1, bAddr2, bAddr3;
    {
        #pragma unroll
        for (int j = 0; j < 4; ++j) {
            int p = p0 + wp * 64 + j * 16 + r16;
            int nt = p / HWSZ, hw = p - nt * HWSZ;
            int hh = hw / WW,  w  = hw - hh * WW;
            int off = ((nt * HP + hh) * WP + w) * 256 + hi * 8;
            if (j == 0) bAddr0 = off; else if (j == 1) bAddr1 = off;
            else if (j == 2) bAddr2 = off; else bAddr3 = off;
        }
    }

    float4v acc[8][4];
    #pragma unroll
    for (int i = 0; i < 8; ++i)
        #pragma unroll
        for (int j = 0; j < 4; ++j) acc[i][j] = (float4v){0.f, 0.f, 0.f, 0.f};

    short8v AX[8], AY[8], BX[4], BY[4];

    // prologue: A(0)->slot0, A(1)->slot1, B(0)->BX; drain thru A(0)=vmcnt(8)
    STGA(0, 0);
    STGA(1, 32);                       // kt=1: rs=0, co=32
    BX[0] = *(const short8v*)(xt + bAddr0);
    BX[1] = *(const short8v*)(xt + bAddr1);
    BX[2] = *(const short8v*)(xt + bAddr2);
    BX[3] = *(const short8v*)(xt + bAddr3);
    VMWAIT(8);
    __builtin_amdgcn_s_barrier();
    __builtin_amdgcn_sched_barrier(0);
    #pragma unroll
    for (int mi = 0; mi < 8; ++mi) AX[mi] = LDAF(0, mi);

    int sl = 0;
    for (int t2 = 0; t2 < 70; t2 += 2) {
        TILE(AX, AY, BX, BY, t2, sl, true, true, 12);
        sl = (sl == 2) ? 0 : sl + 1;
        TILE(AY, AX, BY, BX, t2 + 1, sl, true, true, 12);
        sl = (sl == 2) ? 0 : sl + 1;
    }
    // t=70 (sets X cur): no A(72); B(71)+A(71)-frags; drain thru A(71)=vmcnt(8)
    TILE(AX, AY, BX, BY, 70, sl, false, true, 8);
    sl = (sl == 2) ? 0 : sl + 1;
    // t=71 (sets Y cur): nothing to prefetch
    TILE(AY, AX, BY, BX, 71, sl, false, false, 0);

    // epilogue: bias + store + fused channel-sum
    const int pw = p0 + wp * 64;       // 64-aligned -> whole wave-chunk same image
    const int ntw = pw / HWSZ;
    const int hwb = pw - ntw * HWSZ;
    #pragma unroll
    for (int mi = 0; mi < 8; ++mi) {
        #pragma unroll
        for (int r = 0; r < 4; ++r) {
            const int m = wm * 128 + mi * 16 + hi * 4 + r;
            const float bias = net_b[m];
            float csum = 0.f;
            float* orow = out + ((size_t)ntw * CCH + m) * HWSZ + hwb;
            #pragma unroll
            for (int j = 0; j < 4; ++j) {
                float v = acc[mi][j][r] + bias;
                orow[j * 16 + r16] = v;
                csum += v;
            }
            csum += __shfl_xor(csum, 1);
            csum += __shfl_xor(csum, 2);
            csum += __shfl_xor(csum, 4);
            csum += __shfl_xor(csum, 8);
            if (r16 == 0) atomicAdd(&chansum[ntw * CCH + m], csum);
        }
    }
}

// ---------------- K2: x_g -> lam 1x1 conv -> xg2[n][c] --------------------
__global__ __launch_bounds__(256) void k2_xg(const float* __restrict__ chansum,
                                             const float* __restrict__ lam_w,
                                             const float* __restrict__ lam_b,
                                             float* __restrict__ xg2) {
    int n = blockIdx.x, c = threadIdx.x;
    __shared__ float xs[256];
    float s = 0.f;
    #pragma unroll
    for (int t = 0; t < 8; ++t) s += chansum[(n * 8 + t) * CCH + c];
    xs[c] = s * (1.0f / (3136.f * 8.f));
    __syncthreads();
    float d = lam_b[c];
    const float* row = lam_w + c * 256;
    for (int cc = 0; cc < 256; ++cc) d += row[cc] * xs[cc];
    xg2[n * 256 + c] = d;
}

// ---------------- K3: MLP+BN+softmax weights, m[n][c][t] ------------------
__global__ __launch_bounds__(256) void k3_wgt(const float* __restrict__ chansum,
                                              const float* __restrict__ xg2,
                                              const float* __restrict__ w1,
                                              const float* __restrict__ bg,
                                              const float* __restrict__ bb,
                                              const float* __restrict__ bm,
                                              const float* __restrict__ bv,
                                              const float* __restrict__ w2,
                                              float* __restrict__ wgt,
                                              float* __restrict__ mbuf) {
    int idx = blockIdx.x * 256 + threadIdx.x;    // n*256+c, 2048
    int n = idx >> 8, c = idx & 255;
    float xg = xg2[idx];
    float p[8];
    #pragma unroll
    for (int t = 0; t < 8; ++t)
        p[t] = chansum[(n * 8 + t) * CCH + c] * (1.0f / 3136.f) + xg;
    float hd[16];
    #pragma unroll
    for (int j = 0; j < 16; ++j) {
        float s = 0.f;
        #pragma unroll
        for (int t = 0; t < 8; ++t) s += p[t] * w1[j * 8 + t];
        s = (s - bm[j]) * (bg[j] * rsqrtf(bv[j] + 1e-5f)) + bb[j];
        hd[j] = fmaxf(s, 0.f);
    }
    float lg[3];
    #pragma unroll
    for (int k = 0; k < 3; ++k) {
        float s = 0.f;
        #pragma unroll
        for (int j = 0; j < 16; ++j) s += hd[j] * w2[k * 16 + j];
        lg[k] = s;
    }
    float mx = fmaxf(fmaxf(lg[0], lg[1]), lg[2]);
    float e0 = expf(lg[0] - mx), e1 = expf(lg[1] - mx), e2 = expf(lg[2] - mx);
    float inv = 1.f / (e0 + e1 + e2);
    float wk[3] = {e0 * inv, e1 * inv, e2 * inv};
    #pragma unroll
    for (int k = 0; k < 3; ++k) wgt[idx * 3 + k] = wk[k];
    #pragma unroll
    for (int t = 0; t < 8; ++t) {
        float s = 0.f;
        #pragma unroll
        for (int k = 0; k < 3; ++k) {
            int tt = t + k - 1;
            if (tt >= 0 && tt < 8) s += wk[k] * p[tt];
        }
        mbuf[idx * 8 + t] = s;
    }
}

// ---------------- K4: ME gate[nt][c] --------------------------------------
__global__ __launch_bounds__(256) void k4_gate(const float* __restrict__ mbuf,
                                               const float* __restrict__ me_w,
                                               float* __restrict__ gate) {
    int b = blockIdx.x;          // n*8+t
    int n = b >> 3, t = b & 7;
    int c = threadIdx.x;
    __shared__ float y[256];
    float yv = 0.f;
    if (t < 7) yv = mbuf[(n * 256 + c) * 8 + t + 1] - mbuf[(n * 256 + c) * 8 + t];
    y[c] = yv;
    __syncthreads();
    float yc = me_w[1] * yv;
    if (c > 0)   yc += me_w[0] * y[c - 1];
    if (c < 255) yc += me_w[2] * y[c + 1];
    gate[b * 256 + c] = 1.f / (1.f + expf(-yc));
}

// ---------------- K5: temporal mix + gate, in-place on d_out --------------
__global__ __launch_bounds__(256) void k5_final(float* __restrict__ out,
                                                const float* __restrict__ wgt,
                                                const float* __restrict__ xg2,
                                                const float* __restrict__ gate) {
    int tid = blockIdx.x * 256 + threadIdx.x;   // 2048 * 784
    int hw4 = tid % 784;
    int nc = tid / 784;
    int n = nc >> 8, c = nc & 255;
    float w0 = wgt[nc * 3 + 0], w1 = wgt[nc * 3 + 1], w2 = wgt[nc * 3 + 2];
    float xg = xg2[nc];
    const size_t tstride = (size_t)CCH * HWSZ;
    size_t base = ((size_t)(n * 8) * CCH + c) * HWSZ + hw4 * 4;

    float4v o[8];
    #pragma unroll
    for (int t = 0; t < 8; ++t) o[t] = *(const float4v*)(out + base + t * tstride);

    #pragma unroll
    for (int t = 0; t < 8; ++t) {
        float g = gate[(n * 8 + t) * CCH + c];
        float4v lam;
        #pragma unroll
        for (int q = 0; q < 4; ++q) {
            float v = w1 * (o[t][q] + xg);
            if (t > 0) v += w0 * (o[t - 1][q] + xg);
            if (t < 7) v += w2 * (o[t + 1][q] + xg);
            lam[q] = g * v;
        }
        *(float4v*)(out + base + t * tstride) = lam;
    }
}

extern "C" void kernel_launch(void* const* d_in, const int* in_sizes, int n_in,
                              void* d_out, int out_size, void* d_ws, size_t ws_size,
                              hipStream_t stream) {
    const float* x      = (const float*)d_in[0];
    const float* net_w  = (const float*)d_in[1];
    const float* net_b  = (const float*)d_in[2];
    const float* lam_w  = (const float*)d_in[3];
    const float* lam_b  = (const float*)d_in[4];
    const float* mlp_w1 = (const float*)d_in[5];
    const float* bn_g   = (const float*)d_in[6];
    const float* bn_b   = (const float*)d_in[7];
    const float* bn_m   = (const float*)d_in[8];
    const float* bn_v   = (const float*)d_in[9];
    const float* mlp_w2 = (const float*)d_in[10];
    const float* me_w   = (const float*)d_in[11];
    float* out = (float*)d_out;

    char* ws = (char*)d_ws;
    unsigned short* xt  = (unsigned short*)(ws + OFF_XT);
    unsigned short* wpk = (unsigned short*)(ws + OFF_WPK);
    float* chansum = (float*)(ws + OFF_CS);
    float* xg2     = (float*)(ws + OFF_XG2);
    float* wgt     = (float*)(ws + OFF_WGT);
    float* mbuf    = (float*)(ws + OFF_M);
    float* gate    = (float*)(ws + OFF_GATE);

    hipMemsetAsync(chansum, 0, SZ_CS, stream);
    kw_pack<<<2304, 256, 0, stream>>>(net_w, wpk);
    k0_transpose<<<64 * 56 * 4, 256, 0, stream>>>(x, xt);
    conv_mfma<<<1568, 256, 0, stream>>>(xt, wpk, net_b, out, chansum);
    k2_xg<<<8, 256, 0, stream>>>(chansum, lam_w, lam_b, xg2);
    k3_wgt<<<8, 256, 0, stream>>>(chansum, xg2, mlp_w1, bn_g, bn_b, bn_m, bn_v, mlp_w2, wgt, mbuf);
    k4_gate<<<64, 256, 0, stream>>>(mbuf, me_w, gate);
    k5_final<<<6272, 256, 0, stream>>>(out, wgt, xg2, gate);
}

// Round 11
// 431.690 us; speedup vs baseline: 1.3097x; 1.3097x over previous
//
#include <hip/hip_runtime.h>
#include <hip/hip_bf16.h>
#include <stdint.h>

#define AS1 __attribute__((address_space(1)))
#define AS3 __attribute__((address_space(3)))

typedef __attribute__((ext_vector_type(8))) short short8v;
typedef __attribute__((ext_vector_type(4))) float float4v;

#define NT 64
#define CCH 256
#define HH 56
#define WW 56
#define HWSZ 3136
#define HP 58
#define WP 58

// workspace layout (bytes)
#define OFF_XT   0ull
#define SZ_XT    110231552ull          // 64*58*58*256*2  (bf16 NHWC padded)
#define OFF_WPK  (OFF_XT + SZ_XT)
#define SZ_WPK   1179648ull            // 9*256*256*2
#define OFF_CS   (OFF_WPK + SZ_WPK)
#define SZ_CS    65536ull              // 64*256 f32 channel sums
#define OFF_XG2  (OFF_CS + SZ_CS)
#define SZ_XG2   8192ull               // 8*256 f32
#define OFF_WGT  (OFF_XG2 + SZ_XG2)
#define SZ_WGT   24576ull              // 8*256*3 f32
#define OFF_M    (OFF_WGT + SZ_WGT)
#define SZ_M     65536ull              // 8*256*8 f32
#define OFF_GATE (OFF_M + SZ_M)
#define SZ_GATE  65536ull              // 64*256 f32

__device__ __forceinline__ unsigned short f2bf(float f) {
    unsigned int u = __float_as_uint(f);
    unsigned int r = (u + 0x7fffu + ((u >> 16) & 1u)) >> 16;
    return (unsigned short)r;
}

__device__ __forceinline__ void gload16(const unsigned short* g, unsigned short* l) {
    __builtin_amdgcn_global_load_lds((const AS1 void*)g, (AS3 void*)l, 16, 0, 0);
}

// ---------------- K0: NCHW f32 -> NHWC-padded bf16 (with zero borders) ----
__global__ __launch_bounds__(256) void k0_transpose(const float* __restrict__ x,
                                                    unsigned short* __restrict__ xt) {
    int b = blockIdx.x;              // (nt, h, cb) : 64*56*4
    int cb = b & 3;
    int h  = (b >> 2) % 56;
    int nt = b / (4 * 56);
    int c0 = cb * 64;
    int tid = threadIdx.x;

    __shared__ float xs[64 * 57];    // padded stride 57 to dodge bank conflicts

    const float* src = x + ((size_t)nt * CCH + c0) * HWSZ + h * WW;
    for (int li = tid; li < 896; li += 256) {       // 64 rows * 14 float4
        int row = li / 14, f4 = li % 14;
        float4v v = *(const float4v*)(src + (size_t)row * HWSZ + f4 * 4);
        float* d = &xs[row * 57 + f4 * 4];
        d[0] = v.x; d[1] = v.y; d[2] = v.z; d[3] = v.w;
    }
    __syncthreads();

    unsigned short* dst = xt + (((size_t)nt * HP + (h + 1)) * WP) * CCH + c0;
    for (int job = tid; job < 464; job += 256) {    // 58 ww * 8 cgroups
        int ww = job >> 3, cg = job & 7;
        short8v v;
        if (ww == 0 || ww == 57) {
            v = (short8v){0,0,0,0,0,0,0,0};
        } else {
            #pragma unroll
            for (int jj = 0; jj < 8; ++jj)
                v[jj] = (short)f2bf(xs[(cg * 8 + jj) * 57 + (ww - 1)]);
        }
        *(short8v*)(dst + ww * CCH + cg * 8) = v;
    }
    if (h == 0) {   // zero rows hh=0 and hh=57
        unsigned short* d0  = xt + ((size_t)nt * HP + 0)  * WP * CCH + c0;
        unsigned short* d57 = xt + ((size_t)nt * HP + 57) * WP * CCH + c0;
        short8v z = (short8v){0,0,0,0,0,0,0,0};
        for (int job = tid; job < 464; job += 256) {
            int ww = job >> 3, cg = job & 7;
            *(short8v*)(d0  + ww * CCH + cg * 8) = z;
            *(short8v*)(d57 + ww * CCH + cg * 8) = z;
        }
    }
}

// ---------------- KW: pack conv weights -> [rs][k][c] bf16 ----------------
__global__ __launch_bounds__(256) void kw_pack(const float* __restrict__ nw,
                                               unsigned short* __restrict__ wpk) {
    int idx = blockIdx.x * 256 + threadIdx.x;       // 9*256*256 = 589824
    int rs = idx >> 16;
    int k  = (idx >> 8) & 255;
    int c  = idx & 255;
    wpk[idx] = f2bf(nw[(k * 256 + c) * 9 + rs]);
}

// ---------------- conv: implicit GEMM, 256x128x32, 3-ring, 2 blocks/CU ----
// R11 = R8 (best measured: conv 299us, in-block util ~46%) + TAIL FIX.
// R8's grid 1568 over 512 co-resident blocks = rounds 512/512/512/32: the
// last round ran 32 blocks with 224 CUs idle (~75us, avg busy 77%).
// Fix: grid 1536 = 3*512 exactly; the 32 leftover pixel-tiles fold into the
// 32 EARLIEST-DISPATCHED blocks (swizzled id pb0 < 32 <=> original bid in
// {0,8,...,248}) via an outer loop g = pb0, pb0+1536 -> their 2x work hides
// inside rounds 1-3.  Makespan 4.06 -> ~3.12 rounds.
// Everything else identical to R8: 8 waves of 64x64 (acc 4x4, ~120 regs =
// 4 waves/SIMD from 2 anti-phased blocks), coalesced staging, rotation
// swizzle (2-way = free), 3-ring depth-2 prefetch vmcnt(6).

#define STGALL(bi_, tA_, tB_) do { \
    gload16(wpk + (tA_) + aoffg0, &lds[(bi_) * 8192 + ldsa0]); \
    gload16(wpk + (tA_) + aoffg1, &lds[(bi_) * 8192 + ldsa1]); \
    gload16(xt  + (tB_) + boffg,  &lds[24576 + (bi_) * 4096 + ldsb]); \
} while (0)

#define LDAF(mi) (*(const short8v*)&lds[abase + (wm * 64 + (mi) * 16 + r16) * 32 + pA * 8])
#define LDBF(j)  (*(const short8v*)&lds[bbase + (wp * 64 + (j) * 16 + r16) * 32 + pA * 8])

#define BARSYNC do { \
    __builtin_amdgcn_s_barrier(); \
    __builtin_amdgcn_sched_barrier(0); \
} while (0)

__global__ __launch_bounds__(512, 4) void conv_mfma(const unsigned short* __restrict__ xt,
                                                    const unsigned short* __restrict__ wpk,
                                                    const float* __restrict__ net_b,
                                                    float* __restrict__ out,
                                                    float* __restrict__ chansum) {
    __shared__ unsigned short lds[36864];  // 72 KB: A ring 3x8192, B ring 3x4096

    const int tid  = threadIdx.x;
    const int lane = tid & 63;
    const int wid  = tid >> 6;         // 0..7
    const int wm   = wid >> 1;         // 0..3  (m quarter, 64 rows)
    const int wp   = wid & 1;          // 0..1  (pixel half, 64 px)
    const int r16  = lane & 15;
    const int hi   = lane >> 4;        // 0..3  (k-chunk)
    const int pA   = (hi + (r16 >> 1)) & 3;   // rotation-swizzle read position

    // XCD-aware bijective swizzle: 1536 = 8 * 192
    const int pb0 = (blockIdx.x & 7) * 192 + (blockIdx.x >> 3);

    // A staging precompute (pixel-independent): slot s -> row r = s>>2,
    // pos p = s&3 holds global chunk cg = (p - (r>>1)) & 3; 4 lanes/row
    // cover 64 B contiguous -> coalesced.
    const int cgs = ((tid & 3) - (tid >> 3)) & 3;
    const int aoffg0 = (tid >> 2) * 256 + cgs * 8;   // A rows 0..127
    const int aoffg1 = aoffg0 + 32768;               // A rows 128..255
    const int ldsa0  = tid * 8;
    const int ldsa1  = ldsa0 + 4096;
    const int ldsb   = tid * 8;

    for (int g = pb0; g < 1568; g += 1536) {
        const int p0 = g * 128;

        long boffg;
        {
            int r = tid >> 2;              // pixel row 0..127
            int p = p0 + r;
            int nt = p / HWSZ, hw = p - nt * HWSZ;
            int hh = hw / WW,  w  = hw - hh * WW;
            boffg = ((long)(nt * HP + hh) * WP + w) * 256 + cgs * 8;
        }

        float4v acc[4][4];
        #pragma unroll
        for (int i = 0; i < 4; ++i)
            #pragma unroll
            for (int j = 0; j < 4; ++j) acc[i][j] = (float4v){0.f, 0.f, 0.f, 0.f};

        // prologue: stage tiles 0,1 into ring slots 0,1 (kt: rs=kt>>3, co=(kt&7)*32)
        STGALL(0, 0, 0);
        STGALL(1, 32, 32);

        int cur = 0;
        for (int kt = 0; kt < 72; ++kt) {
            const int abase = cur * 8192;
            const int bbase = 24576 + cur * 4096;

            if (kt < 70) {
                const int ktn = kt + 2;
                int nb2 = cur + 2; if (nb2 >= 3) nb2 -= 3;
                const int rsn = ktn >> 3, con = (ktn & 7) * 32;
                const int tAn = rsn * 65536 + con;
                const int tBn = ((rsn / 3) * WP + (rsn - (rsn / 3) * 3)) * 256 + con;
                STGALL(nb2, tAn, tBn);
                asm volatile("s_waitcnt vmcnt(6)" ::: "memory");
            } else if (kt == 70) {
                asm volatile("s_waitcnt vmcnt(3)" ::: "memory");
            } else {
                asm volatile("s_waitcnt vmcnt(0)" ::: "memory");
            }
            BARSYNC;                       // tile kt sealed for all waves

            short8v afrag[4], bfrag[4];
            #pragma unroll
            for (int mi = 0; mi < 4; ++mi) afrag[mi] = LDAF(mi);
            #pragma unroll
            for (int j = 0; j < 4; ++j) bfrag[j] = LDBF(j);

            asm volatile("s_waitcnt lgkmcnt(0)" ::: "memory");
            __builtin_amdgcn_sched_barrier(0);
            __builtin_amdgcn_s_setprio(1);
            #pragma unroll
            for (int j = 0; j < 4; ++j)
                #pragma unroll
                for (int mi = 0; mi < 4; ++mi)
                    acc[mi][j] = __builtin_amdgcn_mfma_f32_16x16x32_bf16(afrag[mi], bfrag[j], acc[mi][j], 0, 0, 0);
            __builtin_amdgcn_s_setprio(0);
            BARSYNC;                       // WAR: buffer cur free for restage

            ++cur; if (cur >= 3) cur = 0;
        }

        // epilogue: bias + store + fused channel-sum
        const int pw = p0 + wp * 64;   // 64-aligned -> whole wave-chunk same image
        const int ntw = pw / HWSZ;
        const int hwb = pw - ntw * HWSZ;
        #pragma unroll
        for (int mi = 0; mi < 4; ++mi) {
            #pragma unroll
            for (int r = 0; r < 4; ++r) {
                const int m = wm * 64 + mi * 16 + hi * 4 + r;
                const float bias = net_b[m];
                float csum = 0.f;
                float* orow = out + ((size_t)ntw * CCH + m) * HWSZ + hwb;
                #pragma unroll
                for (int j = 0; j < 4; ++j) {
                    float v = acc[mi][j][r] + bias;
                    orow[j * 16 + r16] = v;
                    csum += v;
                }
                csum += __shfl_xor(csum, 1);
                csum += __shfl_xor(csum, 2);
                csum += __shfl_xor(csum, 4);
                csum += __shfl_xor(csum, 8);
                if (r16 == 0) atomicAdd(&chansum[ntw * CCH + m], csum);
            }
        }
    }
}

// ---------------- K2: x_g -> lam 1x1 conv -> xg2[n][c] --------------------
__global__ __launch_bounds__(256) void k2_xg(const float* __restrict__ chansum,
                                             const float* __restrict__ lam_w,
                                             const float* __restrict__ lam_b,
                                             float* __restrict__ xg2) {
    int n = blockIdx.x, c = threadIdx.x;
    __shared__ float xs[256];
    float s = 0.f;
    #pragma unroll
    for (int t = 0; t < 8; ++t) s += chansum[(n * 8 + t) * CCH + c];
    xs[c] = s * (1.0f / (3136.f * 8.f));
    __syncthreads();
    float d = lam_b[c];
    const float* row = lam_w + c * 256;
    for (int cc = 0; cc < 256; ++cc) d += row[cc] * xs[cc];
    xg2[n * 256 + c] = d;
}

// ---------------- K3: MLP+BN+softmax weights, m[n][c][t] ------------------
__global__ __launch_bounds__(256) void k3_wgt(const float* __restrict__ chansum,
                                              const float* __restrict__ xg2,
                                              const float* __restrict__ w1,
                                              const float* __restrict__ bg,
                                              const float* __restrict__ bb,
                                              const float* __restrict__ bm,
                                              const float* __restrict__ bv,
                                              const float* __restrict__ w2,
                                              float* __restrict__ wgt,
                                              float* __restrict__ mbuf) {
    int idx = blockIdx.x * 256 + threadIdx.x;    // n*256+c, 2048
    int n = idx >> 8, c = idx & 255;
    float xg = xg2[idx];
    float p[8];
    #pragma unroll
    for (int t = 0; t < 8; ++t)
        p[t] = chansum[(n * 8 + t) * CCH + c] * (1.0f / 3136.f) + xg;
    float hd[16];
    #pragma unroll
    for (int j = 0; j < 16; ++j) {
        float s = 0.f;
        #pragma unroll
        for (int t = 0; t < 8; ++t) s += p[t] * w1[j * 8 + t];
        s = (s - bm[j]) * (bg[j] * rsqrtf(bv[j] + 1e-5f)) + bb[j];
        hd[j] = fmaxf(s, 0.f);
    }
    float lg[3];
    #pragma unroll
    for (int k = 0; k < 3; ++k) {
        float s = 0.f;
        #pragma unroll
        for (int j = 0; j < 16; ++j) s += hd[j] * w2[k * 16 + j];
        lg[k] = s;
    }
    float mx = fmaxf(fmaxf(lg[0], lg[1]), lg[2]);
    float e0 = expf(lg[0] - mx), e1 = expf(lg[1] - mx), e2 = expf(lg[2] - mx);
    float inv = 1.f / (e0 + e1 + e2);
    float wk[3] = {e0 * inv, e1 * inv, e2 * inv};
    #pragma unroll
    for (int k = 0; k < 3; ++k) wgt[idx * 3 + k] = wk[k];
    #pragma unroll
    for (int t = 0; t < 8; ++t) {
        float s = 0.f;
        #pragma unroll
        for (int k = 0; k < 3; ++k) {
            int tt = t + k - 1;
            if (tt >= 0 && tt < 8) s += wk[k] * p[tt];
        }
        mbuf[idx * 8 + t] = s;
    }
}

// ---------------- K4: ME gate[nt][c] --------------------------------------
__global__ __launch_bounds__(256) void k4_gate(const float* __restrict__ mbuf,
                                               const float* __restrict__ me_w,
                                               float* __restrict__ gate) {
    int b = blockIdx.x;          // n*8+t
    int n = b >> 3, t = b & 7;
    int c = threadIdx.x;
    __shared__ float y[256];
    float yv = 0.f;
    if (t < 7) yv = mbuf[(n * 256 + c) * 8 + t + 1] - mbuf[(n * 256 + c) * 8 + t];
    y[c] = yv;
    __syncthreads();
    float yc = me_w[1] * yv;
    if (c > 0)   yc += me_w[0] * y[c - 1];
    if (c < 255) yc += me_w[2] * y[c + 1];
    gate[b * 256 + c] = 1.f / (1.f + expf(-yc));
}

// ---------------- K5: temporal mix + gate, in-place on d_out --------------
__global__ __launch_bounds__(256) void k5_final(float* __restrict__ out,
                                                const float* __restrict__ wgt,
                                                const float* __restrict__ xg2,
                                                const float* __restrict__ gate) {
    int tid = blockIdx.x * 256 + threadIdx.x;   // 2048 * 784
    int hw4 = tid % 784;
    int nc = tid / 784;
    int n = nc >> 8, c = nc & 255;
    float w0 = wgt[nc * 3 + 0], w1 = wgt[nc * 3 + 1], w2 = wgt[nc * 3 + 2];
    float xg = xg2[nc];
    const size_t tstride = (size_t)CCH * HWSZ;
    size_t base = ((size_t)(n * 8) * CCH + c) * HWSZ + hw4 * 4;

    float4v o[8];
    #pragma unroll
    for (int t = 0; t < 8; ++t) o[t] = *(const float4v*)(out + base + t * tstride);

    #pragma unroll
    for (int t = 0; t < 8; ++t) {
        float g = gate[(n * 8 + t) * CCH + c];
        float4v lam;
        #pragma unroll
        for (int q = 0; q < 4; ++q) {
            float v = w1 * (o[t][q] + xg);
            if (t > 0) v += w0 * (o[t - 1][q] + xg);
            if (t < 7) v += w2 * (o[t + 1][q] + xg);
            lam[q] = g * v;
        }
        *(float4v*)(out + base + t * tstride) = lam;
    }
}

extern "C" void kernel_launch(void* const* d_in, const int* in_sizes, int n_in,
                              void* d_out, int out_size, void* d_ws, size_t ws_size,
                              hipStream_t stream) {
    const float* x      = (const float*)d_in[0];
    const float* net_w  = (const float*)d_in[1];
    const float* net_b  = (const float*)d_in[2];
    const float* lam_w  = (const float*)d_in[3];
    const float* lam_b  = (const float*)d_in[4];
    const float* mlp_w1 = (const float*)d_in[5];
    const float* bn_g   = (const float*)d_in[6];
    const float* bn_b   = (const float*)d_in[7];
    const float* bn_m   = (const float*)d_in[8];
    const float* bn_v   = (const float*)d_in[9];
    const float* mlp_w2 = (const float*)d_in[10];
    const float* me_w   = (const float*)d_in[11];
    float* out = (float*)d_out;

    char* ws = (char*)d_ws;
    unsigned short* xt  = (unsigned short*)(ws + OFF_XT);
    unsigned short* wpk = (unsigned short*)(ws + OFF_WPK);
    float* chansum = (float*)(ws + OFF_CS);
    float* xg2     = (float*)(ws + OFF_XG2);
    float* wgt     = (float*)(ws + OFF_WGT);
    float* mbuf    = (float*)(ws + OFF_M);
    float* gate    = (float*)(ws + OFF_GATE);

    hipMemsetAsync(chansum, 0, SZ_CS, stream);
    kw_pack<<<2304, 256, 0, stream>>>(net_w, wpk);
    k0_transpose<<<64 * 56 * 4, 256, 0, stream>>>(x, xt);
    conv_mfma<<<1536, 512, 0, stream>>>(xt, wpk, net_b, out, chansum);
    k2_xg<<<8, 256, 0, stream>>>(chansum, lam_w, lam_b, xg2);
    k3_wgt<<<8, 256, 0, stream>>>(chansum, xg2, mlp_w1, bn_g, bn_b, bn_m, bn_v, mlp_w2, wgt, mbuf);
    k4_gate<<<64, 256, 0, stream>>>(mbuf, me_w, gate);
    k5_final<<<6272, 256, 0, stream>>>(out, wgt, xg2, gate);
}